// Round 1
// baseline (2999.694 us; speedup 1.0000x reference)
//
#include <hip/hip_runtime.h>
#include <hip/hip_bf16.h>

#define N_NODES 100000
#define D_IN 128
#define D_HID 256
#define D_OUTC 128
#define BN_EPS 1e-5f

// ---------------- SpMM: agg[r] += val * v[c]  (atomic scatter) ----------------
// 32 threads per edge, each thread handles one float4 (4 feats).
__global__ __launch_bounds__(256) void spmm_kernel(
    const int* __restrict__ erows, const int* __restrict__ ecols,
    const float* __restrict__ evals, const float* __restrict__ v,
    float* __restrict__ agg, int E) {
  long long gid = (long long)blockIdx.x * blockDim.x + threadIdx.x;
  int e = (int)(gid >> 5);
  if (e >= E) return;
  int c = (int)(gid & 31);
  int r = erows[e];
  int col = ecols[e];
  float w = evals[e];
  float4 vv = reinterpret_cast<const float4*>(v)[(size_t)col * 32 + c];
  float* dst = agg + (size_t)r * D_IN + c * 4;
  atomicAdd(dst + 0, w * vv.x);
  atomicAdd(dst + 1, w * vv.y);
  atomicAdd(dst + 2, w * vv.z);
  atomicAdd(dst + 3, w * vv.w);
}

// ---------------- GEMM1: h1 = (agg + eps*v) @ W1 + b1 ----------------
// Tile: 64 rows x 128 cols, BK=16. Block 256 threads (16x16); thread -> 4 rows x 8 cols.
__global__ __launch_bounds__(256) void gemm1_kernel(
    const float* __restrict__ agg, const float* __restrict__ v,
    const float* __restrict__ eps_p,
    const float* __restrict__ W1, const float* __restrict__ b1,
    float* __restrict__ h1) {
  __shared__ float As[16][68];   // [k][row], stride 68 floats (16B aligned rows)
  __shared__ float Bs[16][128];  // [k][col]

  int tid = threadIdx.x;
  int tx = tid & 15;   // row group (4 rows each)
  int ty = tid >> 4;   // col group (8 cols each)
  int row0 = blockIdx.x * 64;
  int col0 = blockIdx.y * 128;
  float eps = eps_p[0];

  float acc[4][8];
#pragma unroll
  for (int i = 0; i < 4; ++i)
#pragma unroll
    for (int j = 0; j < 8; ++j) acc[i][j] = 0.f;

  // A-load mapping: 64 rows x 16 k = 1024 elems, 4 per thread (one float4)
  int ar = tid >> 2;           // 0..63
  int ak = (tid & 3) * 4;      // 0,4,8,12
  int arow = row0 + ar;
  // B-load mapping: 16 k x 128 cols = 2048 elems, 8 per thread (two float4)
  int bk = tid >> 4;           // 0..15
  int bc = (tid & 15) * 8;     // 0..120

  for (int k0 = 0; k0 < D_IN; k0 += 16) {
    float4 a4 = make_float4(0.f, 0.f, 0.f, 0.f);
    if (arow < N_NODES) {
      float4 t0 = *reinterpret_cast<const float4*>(agg + (size_t)arow * D_IN + k0 + ak);
      float4 t1 = *reinterpret_cast<const float4*>(v + (size_t)arow * D_IN + k0 + ak);
      a4.x = t0.x + eps * t1.x;
      a4.y = t0.y + eps * t1.y;
      a4.z = t0.z + eps * t1.z;
      a4.w = t0.w + eps * t1.w;
    }
    As[ak + 0][ar] = a4.x;
    As[ak + 1][ar] = a4.y;
    As[ak + 2][ar] = a4.z;
    As[ak + 3][ar] = a4.w;

    const float4* bp = reinterpret_cast<const float4*>(W1 + (size_t)(k0 + bk) * D_HID + col0 + bc);
    float4 b0 = bp[0];
    float4 b1v = bp[1];
    *reinterpret_cast<float4*>(&Bs[bk][bc]) = b0;
    *reinterpret_cast<float4*>(&Bs[bk][bc + 4]) = b1v;
    __syncthreads();

#pragma unroll
    for (int kk = 0; kk < 16; ++kk) {
      float4 a = *reinterpret_cast<const float4*>(&As[kk][tx * 4]);
      float4 p0 = *reinterpret_cast<const float4*>(&Bs[kk][ty * 8]);
      float4 p1 = *reinterpret_cast<const float4*>(&Bs[kk][ty * 8 + 4]);
      float av[4] = {a.x, a.y, a.z, a.w};
      float bv[8] = {p0.x, p0.y, p0.z, p0.w, p1.x, p1.y, p1.z, p1.w};
#pragma unroll
      for (int i = 0; i < 4; ++i)
#pragma unroll
        for (int j = 0; j < 8; ++j) acc[i][j] += av[i] * bv[j];
    }
    __syncthreads();
  }

#pragma unroll
  for (int i = 0; i < 4; ++i) {
    int row = row0 + tx * 4 + i;
    if (row >= N_NODES) continue;
    float* cp = h1 + (size_t)row * D_HID + col0 + ty * 8;
#pragma unroll
    for (int j2 = 0; j2 < 2; ++j2) {
      float4 o;
      o.x = acc[i][j2 * 4 + 0] + b1[col0 + ty * 8 + j2 * 4 + 0];
      o.y = acc[i][j2 * 4 + 1] + b1[col0 + ty * 8 + j2 * 4 + 1];
      o.z = acc[i][j2 * 4 + 2] + b1[col0 + ty * 8 + j2 * 4 + 2];
      o.w = acc[i][j2 * 4 + 3] + b1[col0 + ty * 8 + j2 * 4 + 3];
      reinterpret_cast<float4*>(cp)[j2] = o;
    }
  }
}

// ---------------- GEMM2: out = relu_bn1(h1) @ W2 + b2 (raw, pre-BN2) ----------------
// K=256, out cols=128 (full). Same tiling.
__global__ __launch_bounds__(256) void gemm2_kernel(
    const float* __restrict__ h1, const float* __restrict__ ss1,
    const float* __restrict__ W2, const float* __restrict__ b2,
    float* __restrict__ out) {
  __shared__ float As[16][68];
  __shared__ float Bs[16][128];

  int tid = threadIdx.x;
  int tx = tid & 15;
  int ty = tid >> 4;
  int row0 = blockIdx.x * 64;

  float acc[4][8];
#pragma unroll
  for (int i = 0; i < 4; ++i)
#pragma unroll
    for (int j = 0; j < 8; ++j) acc[i][j] = 0.f;

  int ar = tid >> 2;
  int ak = (tid & 3) * 4;
  int arow = row0 + ar;
  int bk = tid >> 4;
  int bc = (tid & 15) * 8;

  for (int k0 = 0; k0 < D_HID; k0 += 16) {
    float4 a4 = make_float4(0.f, 0.f, 0.f, 0.f);
    if (arow < N_NODES) {
      float4 t0 = *reinterpret_cast<const float4*>(h1 + (size_t)arow * D_HID + k0 + ak);
      float4 sc = *reinterpret_cast<const float4*>(&ss1[k0 + ak]);
      float4 sh = *reinterpret_cast<const float4*>(&ss1[D_HID + k0 + ak]);
      a4.x = fmaxf(t0.x * sc.x + sh.x, 0.f);
      a4.y = fmaxf(t0.y * sc.y + sh.y, 0.f);
      a4.z = fmaxf(t0.z * sc.z + sh.z, 0.f);
      a4.w = fmaxf(t0.w * sc.w + sh.w, 0.f);
    }
    As[ak + 0][ar] = a4.x;
    As[ak + 1][ar] = a4.y;
    As[ak + 2][ar] = a4.z;
    As[ak + 3][ar] = a4.w;

    const float4* bp = reinterpret_cast<const float4*>(W2 + (size_t)(k0 + bk) * D_OUTC + bc);
    float4 b0 = bp[0];
    float4 b1v = bp[1];
    *reinterpret_cast<float4*>(&Bs[bk][bc]) = b0;
    *reinterpret_cast<float4*>(&Bs[bk][bc + 4]) = b1v;
    __syncthreads();

#pragma unroll
    for (int kk = 0; kk < 16; ++kk) {
      float4 a = *reinterpret_cast<const float4*>(&As[kk][tx * 4]);
      float4 p0 = *reinterpret_cast<const float4*>(&Bs[kk][ty * 8]);
      float4 p1 = *reinterpret_cast<const float4*>(&Bs[kk][ty * 8 + 4]);
      float av[4] = {a.x, a.y, a.z, a.w};
      float bv[8] = {p0.x, p0.y, p0.z, p0.w, p1.x, p1.y, p1.z, p1.w};
#pragma unroll
      for (int i = 0; i < 4; ++i)
#pragma unroll
        for (int j = 0; j < 8; ++j) acc[i][j] += av[i] * bv[j];
    }
    __syncthreads();
  }

#pragma unroll
  for (int i = 0; i < 4; ++i) {
    int row = row0 + tx * 4 + i;
    if (row >= N_NODES) continue;
    float* cp = out + (size_t)row * D_OUTC + ty * 8;
#pragma unroll
    for (int j2 = 0; j2 < 2; ++j2) {
      float4 o;
      o.x = acc[i][j2 * 4 + 0] + b2[ty * 8 + j2 * 4 + 0];
      o.y = acc[i][j2 * 4 + 1] + b2[ty * 8 + j2 * 4 + 1];
      o.z = acc[i][j2 * 4 + 2] + b2[ty * 8 + j2 * 4 + 2];
      o.w = acc[i][j2 * 4 + 3] + b2[ty * 8 + j2 * 4 + 3];
      reinterpret_cast<float4*>(cp)[j2] = o;
    }
  }
}

// ---------------- column stats: sum & sumsq per column ----------------
template <int C>
__global__ void colstats_kernel(const float* __restrict__ x, int rows,
                                float* __restrict__ stats) {
  int col = threadIdx.x;  // blockDim == C
  float s = 0.f, s2 = 0.f;
  for (int r = blockIdx.x; r < rows; r += gridDim.x) {
    float val = x[(size_t)r * C + col];
    s += val;
    s2 += val * val;
  }
  atomicAdd(&stats[col], s);
  atomicAdd(&stats[C + col], s2);
}

// ---------------- finalize: stats -> scale/shift ----------------
template <int C>
__global__ void finalize_kernel(const float* __restrict__ stats,
                                const float* __restrict__ g,
                                const float* __restrict__ be,
                                float* __restrict__ ss) {
  int j = threadIdx.x;
  float inv_n = 1.0f / (float)N_NODES;
  float mu = stats[j] * inv_n;
  float var = stats[C + j] * inv_n - mu * mu;
  float sc = g[j] * rsqrtf(var + BN_EPS);
  ss[j] = sc;
  ss[C + j] = be[j] - mu * sc;
}

// ---------------- final elementwise BN2 + ReLU, in-place on out ----------------
__global__ __launch_bounds__(256) void bnrelu_kernel(float* __restrict__ out,
                                                     const float* __restrict__ ss) {
  __shared__ float sc[D_OUTC], sh[D_OUTC];
  if (threadIdx.x < D_OUTC) {
    sc[threadIdx.x] = ss[threadIdx.x];
    sh[threadIdx.x] = ss[D_OUTC + threadIdx.x];
  }
  __syncthreads();
  size_t total = (size_t)N_NODES * (D_OUTC / 4);
  for (size_t i = (size_t)blockIdx.x * blockDim.x + threadIdx.x; i < total;
       i += (size_t)gridDim.x * blockDim.x) {
    float4 o = reinterpret_cast<float4*>(out)[i];
    int c = ((int)(i & 31)) * 4;
    o.x = fmaxf(o.x * sc[c + 0] + sh[c + 0], 0.f);
    o.y = fmaxf(o.y * sc[c + 1] + sh[c + 1], 0.f);
    o.z = fmaxf(o.z * sc[c + 2] + sh[c + 2], 0.f);
    o.w = fmaxf(o.w * sc[c + 3] + sh[c + 3], 0.f);
    reinterpret_cast<float4*>(out)[i] = o;
  }
}

extern "C" void kernel_launch(void* const* d_in, const int* in_sizes, int n_in,
                              void* d_out, int out_size, void* d_ws, size_t ws_size,
                              hipStream_t stream) {
  const float* v = (const float*)d_in[0];
  const int* erows = (const int*)d_in[1];
  const int* ecols = (const int*)d_in[2];
  const float* evals = (const float*)d_in[3];
  const float* eps = (const float*)d_in[4];
  const float* W1 = (const float*)d_in[5];
  const float* b1 = (const float*)d_in[6];
  const float* g1 = (const float*)d_in[7];
  const float* be1 = (const float*)d_in[8];
  const float* W2 = (const float*)d_in[9];
  const float* b2 = (const float*)d_in[10];
  const float* g2 = (const float*)d_in[11];
  const float* be2 = (const float*)d_in[12];
  float* out = (float*)d_out;
  int E = in_sizes[1];

  float* agg = (float*)d_ws;                          // N*128
  float* h1 = agg + (size_t)N_NODES * D_IN;           // N*256
  float* stats1 = h1 + (size_t)N_NODES * D_HID;       // 512
  float* ss1 = stats1 + 2 * D_HID;                    // 512
  float* stats2 = ss1 + 2 * D_HID;                    // 256
  float* ss2 = stats2 + 2 * D_OUTC;                   // 256

  hipMemsetAsync(agg, 0, (size_t)N_NODES * D_IN * sizeof(float), stream);
  hipMemsetAsync(stats1, 0, (2 * D_HID + 2 * D_HID + 2 * D_OUTC + 2 * D_OUTC) * sizeof(float), stream);

  // SpMM
  {
    long long total = (long long)E * 32;
    int blocks = (int)((total + 255) / 256);
    spmm_kernel<<<blocks, 256, 0, stream>>>(erows, ecols, evals, v, agg, E);
  }
  // GEMM1 + bias (raw pre-BN h1)
  {
    dim3 grid((N_NODES + 63) / 64, 2);
    gemm1_kernel<<<grid, 256, 0, stream>>>(agg, v, eps, W1, b1, h1);
  }
  // BN1 stats + finalize
  colstats_kernel<D_HID><<<1024, D_HID, 0, stream>>>(h1, N_NODES, stats1);
  finalize_kernel<D_HID><<<1, D_HID, 0, stream>>>(stats1, g1, be1, ss1);
  // GEMM2 with fused BN1+ReLU on A-load (raw pre-BN2 out)
  {
    dim3 grid((N_NODES + 63) / 64, 1);
    gemm2_kernel<<<grid, 256, 0, stream>>>(h1, ss1, W2, b2, out);
  }
  // BN2 stats + finalize + in-place BN2+ReLU
  colstats_kernel<D_OUTC><<<1024, D_OUTC, 0, stream>>>(out, N_NODES, stats2);
  finalize_kernel<D_OUTC><<<1, D_OUTC, 0, stream>>>(stats2, g2, be2, ss2);
  bnrelu_kernel<<<2048, 256, 0, stream>>>(out, ss2);
}

// Round 2
// 661.919 us; speedup vs baseline: 4.5318x; 4.5318x over previous
//
#include <hip/hip_runtime.h>
#include <hip/hip_bf16.h>

#define N_NODES 100000
#define D_IN 128
#define D_HID 256
#define D_OUTC 128
#define BN_EPS 1e-5f

// ============ CSR build: histogram -> scan -> scatter ============

__global__ __launch_bounds__(256) void hist_kernel(const int* __restrict__ erows,
                                                   int* __restrict__ cnt, int E) {
  int e = blockIdx.x * 256 + threadIdx.x;
  if (e < E) atomicAdd(&cnt[erows[e]], 1);
}

// per-block (1024 elems) reduction of counts
__global__ __launch_bounds__(256) void scan_reduce_kernel(const int* __restrict__ cnt,
                                                          int* __restrict__ partials, int n) {
  __shared__ int red[256];
  int tid = threadIdx.x;
  int base = blockIdx.x * 1024 + tid * 4;
  int s = 0;
  if (base + 3 < n) {
    int4 t = *reinterpret_cast<const int4*>(cnt + base);
    s = t.x + t.y + t.z + t.w;
  } else {
    for (int i = 0; i < 4; ++i)
      if (base + i < n) s += cnt[base + i];
  }
  red[tid] = s;
  __syncthreads();
  for (int off = 128; off > 0; off >>= 1) {
    if (tid < off) red[tid] += red[tid + off];
    __syncthreads();
  }
  if (tid == 0) partials[blockIdx.x] = red[0];
}

// single block: exclusive scan of <=128 partials, in place; also row_start[n]=E
__global__ __launch_bounds__(128) void scan_partials_kernel(int* __restrict__ partials, int nb,
                                                            int* __restrict__ row_start, int n,
                                                            int E) {
  __shared__ int buf[128];
  int tid = threadIdx.x;
  int orig = (tid < nb) ? partials[tid] : 0;
  buf[tid] = orig;
  __syncthreads();
  for (int off = 1; off < 128; off <<= 1) {
    int t = (tid >= off) ? buf[tid - off] : 0;
    __syncthreads();
    buf[tid] += t;
    __syncthreads();
  }
  if (tid < nb) partials[tid] = buf[tid] - orig;  // exclusive
  if (tid == 0) row_start[n] = E;
}

// per-block exclusive scan over its 1024 counts + block offset; writes row_start & cursor
__global__ __launch_bounds__(256) void scan_block_kernel(const int* __restrict__ cnt,
                                                         const int* __restrict__ partials,
                                                         int* __restrict__ row_start,
                                                         int* __restrict__ cursor, int n) {
  __shared__ int sums[256];
  int tid = threadIdx.x;
  int base = blockIdx.x * 1024 + tid * 4;
  int v0 = 0, v1 = 0, v2 = 0, v3 = 0;
  if (base + 3 < n) {
    int4 t = *reinterpret_cast<const int4*>(cnt + base);
    v0 = t.x; v1 = t.y; v2 = t.z; v3 = t.w;
  } else {
    if (base + 0 < n) v0 = cnt[base + 0];
    if (base + 1 < n) v1 = cnt[base + 1];
    if (base + 2 < n) v2 = cnt[base + 2];
    if (base + 3 < n) v3 = cnt[base + 3];
  }
  int ls = v0 + v1 + v2 + v3;
  int orig = ls;
  sums[tid] = ls;
  __syncthreads();
  for (int off = 1; off < 256; off <<= 1) {
    int t = (tid >= off) ? sums[tid - off] : 0;
    __syncthreads();
    sums[tid] += t;
    __syncthreads();
  }
  int run = sums[tid] - orig + partials[blockIdx.x];
  if (base + 0 < n) { row_start[base + 0] = run; cursor[base + 0] = run; run += v0; }
  if (base + 1 < n) { row_start[base + 1] = run; cursor[base + 1] = run; run += v1; }
  if (base + 2 < n) { row_start[base + 2] = run; cursor[base + 2] = run; run += v2; }
  if (base + 3 < n) { row_start[base + 3] = run; cursor[base + 3] = run; run += v3; }
}

__global__ __launch_bounds__(256) void scatter_kernel(const int* __restrict__ erows,
                                                      const int* __restrict__ ecols,
                                                      const float* __restrict__ evals,
                                                      int* __restrict__ cursor,
                                                      int* __restrict__ scol,
                                                      float* __restrict__ sval, int E) {
  int e = blockIdx.x * 256 + threadIdx.x;
  if (e >= E) return;
  int r = erows[e];
  int pos = atomicAdd(&cursor[r], 1);
  scol[pos] = ecols[e];
  sval[pos] = evals[e];
}

// ============ Gather SpMM: one wave per row, atomic-free ============
__global__ __launch_bounds__(256) void gather_kernel(const int* __restrict__ row_start,
                                                     const int* __restrict__ scol,
                                                     const float* __restrict__ sval,
                                                     const float* __restrict__ v,
                                                     float* __restrict__ agg) {
  int wid = blockIdx.x * 4 + (threadIdx.x >> 6);
  if (wid >= N_NODES) return;
  int lane = threadIdx.x & 63;
  int s = row_start[wid];
  int epos_end = row_start[wid + 1];
  const float2* v2 = reinterpret_cast<const float2*>(v);
  float2 acc = make_float2(0.f, 0.f);
  for (int e = s; e < epos_end; ++e) {
    int c = scol[e];
    float w = sval[e];
    float2 t = v2[(size_t)c * 64 + lane];
    acc.x += w * t.x;
    acc.y += w * t.y;
  }
  reinterpret_cast<float2*>(agg)[(size_t)wid * 64 + lane] = acc;
}

// ============ GEMM1: h1 = (agg + eps*v) @ W1 + b1 ============
__global__ __launch_bounds__(256) void gemm1_kernel(
    const float* __restrict__ agg, const float* __restrict__ v,
    const float* __restrict__ eps_p,
    const float* __restrict__ W1, const float* __restrict__ b1,
    float* __restrict__ h1) {
  __shared__ float As[16][68];
  __shared__ float Bs[16][128];

  int tid = threadIdx.x;
  int tx = tid & 15;
  int ty = tid >> 4;
  int row0 = blockIdx.x * 64;
  int col0 = blockIdx.y * 128;
  float eps = eps_p[0];

  float acc[4][8];
#pragma unroll
  for (int i = 0; i < 4; ++i)
#pragma unroll
    for (int j = 0; j < 8; ++j) acc[i][j] = 0.f;

  int ar = tid >> 2;
  int ak = (tid & 3) * 4;
  int arow = row0 + ar;
  int bk = tid >> 4;
  int bc = (tid & 15) * 8;

  for (int k0 = 0; k0 < D_IN; k0 += 16) {
    float4 a4 = make_float4(0.f, 0.f, 0.f, 0.f);
    if (arow < N_NODES) {
      float4 t0 = *reinterpret_cast<const float4*>(agg + (size_t)arow * D_IN + k0 + ak);
      float4 t1 = *reinterpret_cast<const float4*>(v + (size_t)arow * D_IN + k0 + ak);
      a4.x = t0.x + eps * t1.x;
      a4.y = t0.y + eps * t1.y;
      a4.z = t0.z + eps * t1.z;
      a4.w = t0.w + eps * t1.w;
    }
    As[ak + 0][ar] = a4.x;
    As[ak + 1][ar] = a4.y;
    As[ak + 2][ar] = a4.z;
    As[ak + 3][ar] = a4.w;

    const float4* bp = reinterpret_cast<const float4*>(W1 + (size_t)(k0 + bk) * D_HID + col0 + bc);
    float4 b0 = bp[0];
    float4 b1v = bp[1];
    *reinterpret_cast<float4*>(&Bs[bk][bc]) = b0;
    *reinterpret_cast<float4*>(&Bs[bk][bc + 4]) = b1v;
    __syncthreads();

#pragma unroll
    for (int kk = 0; kk < 16; ++kk) {
      float4 a = *reinterpret_cast<const float4*>(&As[kk][tx * 4]);
      float4 p0 = *reinterpret_cast<const float4*>(&Bs[kk][ty * 8]);
      float4 p1 = *reinterpret_cast<const float4*>(&Bs[kk][ty * 8 + 4]);
      float av[4] = {a.x, a.y, a.z, a.w};
      float bv[8] = {p0.x, p0.y, p0.z, p0.w, p1.x, p1.y, p1.z, p1.w};
#pragma unroll
      for (int i = 0; i < 4; ++i)
#pragma unroll
        for (int j = 0; j < 8; ++j) acc[i][j] += av[i] * bv[j];
    }
    __syncthreads();
  }

#pragma unroll
  for (int i = 0; i < 4; ++i) {
    int row = row0 + tx * 4 + i;
    if (row >= N_NODES) continue;
    float* cp = h1 + (size_t)row * D_HID + col0 + ty * 8;
#pragma unroll
    for (int j2 = 0; j2 < 2; ++j2) {
      float4 o;
      o.x = acc[i][j2 * 4 + 0] + b1[col0 + ty * 8 + j2 * 4 + 0];
      o.y = acc[i][j2 * 4 + 1] + b1[col0 + ty * 8 + j2 * 4 + 1];
      o.z = acc[i][j2 * 4 + 2] + b1[col0 + ty * 8 + j2 * 4 + 2];
      o.w = acc[i][j2 * 4 + 3] + b1[col0 + ty * 8 + j2 * 4 + 3];
      reinterpret_cast<float4*>(cp)[j2] = o;
    }
  }
}

// ============ GEMM2: out = relu_bn1(h1) @ W2 + b2 (raw, pre-BN2) ============
__global__ __launch_bounds__(256) void gemm2_kernel(
    const float* __restrict__ h1, const float* __restrict__ ss1,
    const float* __restrict__ W2, const float* __restrict__ b2,
    float* __restrict__ out) {
  __shared__ float As[16][68];
  __shared__ float Bs[16][128];

  int tid = threadIdx.x;
  int tx = tid & 15;
  int ty = tid >> 4;
  int row0 = blockIdx.x * 64;

  float acc[4][8];
#pragma unroll
  for (int i = 0; i < 4; ++i)
#pragma unroll
    for (int j = 0; j < 8; ++j) acc[i][j] = 0.f;

  int ar = tid >> 2;
  int ak = (tid & 3) * 4;
  int arow = row0 + ar;
  int bk = tid >> 4;
  int bc = (tid & 15) * 8;

  for (int k0 = 0; k0 < D_HID; k0 += 16) {
    float4 a4 = make_float4(0.f, 0.f, 0.f, 0.f);
    if (arow < N_NODES) {
      float4 t0 = *reinterpret_cast<const float4*>(h1 + (size_t)arow * D_HID + k0 + ak);
      float4 sc = *reinterpret_cast<const float4*>(&ss1[k0 + ak]);
      float4 sh = *reinterpret_cast<const float4*>(&ss1[D_HID + k0 + ak]);
      a4.x = fmaxf(t0.x * sc.x + sh.x, 0.f);
      a4.y = fmaxf(t0.y * sc.y + sh.y, 0.f);
      a4.z = fmaxf(t0.z * sc.z + sh.z, 0.f);
      a4.w = fmaxf(t0.w * sc.w + sh.w, 0.f);
    }
    As[ak + 0][ar] = a4.x;
    As[ak + 1][ar] = a4.y;
    As[ak + 2][ar] = a4.z;
    As[ak + 3][ar] = a4.w;

    const float4* bp = reinterpret_cast<const float4*>(W2 + (size_t)(k0 + bk) * D_OUTC + bc);
    float4 b0 = bp[0];
    float4 b1v = bp[1];
    *reinterpret_cast<float4*>(&Bs[bk][bc]) = b0;
    *reinterpret_cast<float4*>(&Bs[bk][bc + 4]) = b1v;
    __syncthreads();

#pragma unroll
    for (int kk = 0; kk < 16; ++kk) {
      float4 a = *reinterpret_cast<const float4*>(&As[kk][tx * 4]);
      float4 p0 = *reinterpret_cast<const float4*>(&Bs[kk][ty * 8]);
      float4 p1 = *reinterpret_cast<const float4*>(&Bs[kk][ty * 8 + 4]);
      float av[4] = {a.x, a.y, a.z, a.w};
      float bv[8] = {p0.x, p0.y, p0.z, p0.w, p1.x, p1.y, p1.z, p1.w};
#pragma unroll
      for (int i = 0; i < 4; ++i)
#pragma unroll
        for (int j = 0; j < 8; ++j) acc[i][j] += av[i] * bv[j];
    }
    __syncthreads();
  }

#pragma unroll
  for (int i = 0; i < 4; ++i) {
    int row = row0 + tx * 4 + i;
    if (row >= N_NODES) continue;
    float* cp = out + (size_t)row * D_OUTC + ty * 8;
#pragma unroll
    for (int j2 = 0; j2 < 2; ++j2) {
      float4 o;
      o.x = acc[i][j2 * 4 + 0] + b2[ty * 8 + j2 * 4 + 0];
      o.y = acc[i][j2 * 4 + 1] + b2[ty * 8 + j2 * 4 + 1];
      o.z = acc[i][j2 * 4 + 2] + b2[ty * 8 + j2 * 4 + 2];
      o.w = acc[i][j2 * 4 + 3] + b2[ty * 8 + j2 * 4 + 3];
      reinterpret_cast<float4*>(cp)[j2] = o;
    }
  }
}

// ============ column stats: sum & sumsq per column ============
template <int C>
__global__ void colstats_kernel(const float* __restrict__ x, int rows,
                                float* __restrict__ stats) {
  int col = threadIdx.x;  // blockDim == C
  float s = 0.f, s2 = 0.f;
  for (int r = blockIdx.x; r < rows; r += gridDim.x) {
    float val = x[(size_t)r * C + col];
    s += val;
    s2 += val * val;
  }
  atomicAdd(&stats[col], s);
  atomicAdd(&stats[C + col], s2);
}

template <int C>
__global__ void finalize_kernel(const float* __restrict__ stats,
                                const float* __restrict__ g,
                                const float* __restrict__ be,
                                float* __restrict__ ss) {
  int j = threadIdx.x;
  float inv_n = 1.0f / (float)N_NODES;
  float mu = stats[j] * inv_n;
  float var = stats[C + j] * inv_n - mu * mu;
  float sc = g[j] * rsqrtf(var + BN_EPS);
  ss[j] = sc;
  ss[C + j] = be[j] - mu * sc;
}

__global__ __launch_bounds__(256) void bnrelu_kernel(float* __restrict__ out,
                                                     const float* __restrict__ ss) {
  __shared__ float sc[D_OUTC], sh[D_OUTC];
  if (threadIdx.x < D_OUTC) {
    sc[threadIdx.x] = ss[threadIdx.x];
    sh[threadIdx.x] = ss[D_OUTC + threadIdx.x];
  }
  __syncthreads();
  size_t total = (size_t)N_NODES * (D_OUTC / 4);
  for (size_t i = (size_t)blockIdx.x * blockDim.x + threadIdx.x; i < total;
       i += (size_t)gridDim.x * blockDim.x) {
    float4 o = reinterpret_cast<float4*>(out)[i];
    int c = ((int)(i & 31)) * 4;
    o.x = fmaxf(o.x * sc[c + 0] + sh[c + 0], 0.f);
    o.y = fmaxf(o.y * sc[c + 1] + sh[c + 1], 0.f);
    o.z = fmaxf(o.z * sc[c + 2] + sh[c + 2], 0.f);
    o.w = fmaxf(o.w * sc[c + 3] + sh[c + 3], 0.f);
    reinterpret_cast<float4*>(out)[i] = o;
  }
}

extern "C" void kernel_launch(void* const* d_in, const int* in_sizes, int n_in,
                              void* d_out, int out_size, void* d_ws, size_t ws_size,
                              hipStream_t stream) {
  const float* v = (const float*)d_in[0];
  const int* erows = (const int*)d_in[1];
  const int* ecols = (const int*)d_in[2];
  const float* evals = (const float*)d_in[3];
  const float* eps = (const float*)d_in[4];
  const float* W1 = (const float*)d_in[5];
  const float* b1 = (const float*)d_in[6];
  const float* g1 = (const float*)d_in[7];
  const float* be1 = (const float*)d_in[8];
  const float* W2 = (const float*)d_in[9];
  const float* b2 = (const float*)d_in[10];
  const float* g2 = (const float*)d_in[11];
  const float* be2 = (const float*)d_in[12];
  float* out = (float*)d_out;
  int E = in_sizes[1];

  // workspace layout (16B-aligned chunks)
  float* agg = (float*)d_ws;                          // N*128 floats
  float* h1 = agg + (size_t)N_NODES * D_IN;           // N*256 floats
  // CSR scratch overlays h1 (dead until gemm1 writes it)
  int* scol = (int*)h1;                               // E ints
  float* sval = (float*)(scol + ((E + 3) & ~3));      // E floats
  float* stats1 = h1 + (size_t)N_NODES * D_HID;       // 512
  float* ss1 = stats1 + 2 * D_HID;                    // 512
  float* stats2 = ss1 + 2 * D_HID;                    // 256
  float* ss2 = stats2 + 2 * D_OUTC;                   // 256
  int* row_start = (int*)(ss2 + 2 * D_OUTC);          // N+1 (padded to 100004)
  int* cursor = row_start + 100004;                   // N
  int* partials = cursor + N_NODES;                   // 128

  const int NB = (N_NODES + 1023) / 1024;  // 98 scan blocks

  hipMemsetAsync(stats1, 0, (2 * D_HID + 2 * D_HID + 2 * D_OUTC + 2 * D_OUTC) * sizeof(float), stream);
  hipMemsetAsync(cursor, 0, N_NODES * sizeof(int), stream);

  // --- CSR build ---
  hist_kernel<<<(E + 255) / 256, 256, 0, stream>>>(erows, cursor, E);
  scan_reduce_kernel<<<NB, 256, 0, stream>>>(cursor, partials, N_NODES);
  scan_partials_kernel<<<1, 128, 0, stream>>>(partials, NB, row_start, N_NODES, E);
  scan_block_kernel<<<NB, 256, 0, stream>>>(cursor, partials, row_start, cursor, N_NODES);
  scatter_kernel<<<(E + 255) / 256, 256, 0, stream>>>(erows, ecols, evals, cursor, scol, sval, E);

  // --- gather SpMM (atomic-free) ---
  gather_kernel<<<(N_NODES + 3) / 4, 256, 0, stream>>>(row_start, scol, sval, v, agg);

  // --- GEMM1 + bias (raw pre-BN h1) ---
  {
    dim3 grid((N_NODES + 63) / 64, 2);
    gemm1_kernel<<<grid, 256, 0, stream>>>(agg, v, eps, W1, b1, h1);
  }
  colstats_kernel<D_HID><<<1024, D_HID, 0, stream>>>(h1, N_NODES, stats1);
  finalize_kernel<D_HID><<<1, D_HID, 0, stream>>>(stats1, g1, be1, ss1);
  {
    dim3 grid((N_NODES + 63) / 64, 1);
    gemm2_kernel<<<grid, 256, 0, stream>>>(h1, ss1, W2, b2, out);
  }
  colstats_kernel<D_OUTC><<<1024, D_OUTC, 0, stream>>>(out, N_NODES, stats2);
  finalize_kernel<D_OUTC><<<1, D_OUTC, 0, stream>>>(stats2, g2, be2, ss2);
  bnrelu_kernel<<<2048, 256, 0, stream>>>(out, ss2);
}

// Round 3
// 627.491 us; speedup vs baseline: 4.7805x; 1.0549x over previous
//
#include <hip/hip_runtime.h>
#include <hip/hip_bf16.h>

#define N_NODES 100000
#define D_IN 128
#define D_HID 256
#define D_OUTC 128
#define BN_EPS 1e-5f

typedef __attribute__((ext_vector_type(8))) short short8;
typedef __attribute__((ext_vector_type(4))) float f32x4;

__device__ __forceinline__ unsigned short f2bf(float f) {
  unsigned int u = __float_as_uint(f);
  unsigned int r = u + 0x7fffu + ((u >> 16) & 1u);
  return (unsigned short)(r >> 16);
}
__device__ __forceinline__ float bf2f(unsigned short h) {
  return __uint_as_float(((unsigned int)h) << 16);
}

// ============ conversions ============
__global__ __launch_bounds__(256) void conv_v_kernel(const float* __restrict__ v,
                                                     unsigned short* __restrict__ v_bf) {
  int i = blockIdx.x * 256 + threadIdx.x;  // one per 8 elems; grid covers exactly
  const float4* v4 = reinterpret_cast<const float4*>(v);
  float4 a = v4[i * 2];
  float4 b = v4[i * 2 + 1];
  short8 o;
  o[0] = (short)f2bf(a.x); o[1] = (short)f2bf(a.y);
  o[2] = (short)f2bf(a.z); o[3] = (short)f2bf(a.w);
  o[4] = (short)f2bf(b.x); o[5] = (short)f2bf(b.y);
  o[6] = (short)f2bf(b.z); o[7] = (short)f2bf(b.w);
  *reinterpret_cast<short8*>(v_bf + (size_t)i * 8) = o;
}

// transpose+convert W1[128,256]->w1t[256,128], W2[256,128]->w2t[128,256]
__global__ __launch_bounds__(256) void conv_w_kernel(const float* __restrict__ W1,
                                                     const float* __restrict__ W2,
                                                     unsigned short* __restrict__ w1t,
                                                     unsigned short* __restrict__ w2t) {
  int idx = blockIdx.x * 256 + threadIdx.x;
  if (idx < 128 * 256) {
    int n = idx >> 7, k = idx & 127;           // w1t[n][k] = W1[k][n]
    w1t[idx] = f2bf(W1[(size_t)k * 256 + n]);
  } else {
    int i2 = idx - 128 * 256;
    int n = i2 >> 8, k = i2 & 255;             // w2t[n][k] = W2[k][n]
    w2t[i2] = f2bf(W2[(size_t)k * 128 + n]);
  }
}

// ============ CSR build ============
__global__ __launch_bounds__(256) void hist_kernel(const int* __restrict__ erows,
                                                   int* __restrict__ cnt, int E) {
  int e = blockIdx.x * 256 + threadIdx.x;
  if (e < E) atomicAdd(&cnt[erows[e]], 1);
}

__global__ __launch_bounds__(256) void scan_reduce_kernel(const int* __restrict__ cnt,
                                                          int* __restrict__ partials, int n) {
  __shared__ int red[256];
  int tid = threadIdx.x;
  int base = blockIdx.x * 1024 + tid * 4;
  int s = 0;
  if (base + 3 < n) {
    int4 t = *reinterpret_cast<const int4*>(cnt + base);
    s = t.x + t.y + t.z + t.w;
  } else {
    for (int i = 0; i < 4; ++i)
      if (base + i < n) s += cnt[base + i];
  }
  red[tid] = s;
  __syncthreads();
  for (int off = 128; off > 0; off >>= 1) {
    if (tid < off) red[tid] += red[tid + off];
    __syncthreads();
  }
  if (tid == 0) partials[blockIdx.x] = red[0];
}

__global__ __launch_bounds__(128) void scan_partials_kernel(int* __restrict__ partials, int nb,
                                                            int* __restrict__ row_start, int n,
                                                            int E) {
  __shared__ int buf[128];
  int tid = threadIdx.x;
  int orig = (tid < nb) ? partials[tid] : 0;
  buf[tid] = orig;
  __syncthreads();
  for (int off = 1; off < 128; off <<= 1) {
    int t = (tid >= off) ? buf[tid - off] : 0;
    __syncthreads();
    buf[tid] += t;
    __syncthreads();
  }
  if (tid < nb) partials[tid] = buf[tid] - orig;
  if (tid == 0) row_start[n] = E;
}

__global__ __launch_bounds__(256) void scan_block_kernel(const int* __restrict__ cnt,
                                                         const int* __restrict__ partials,
                                                         int* __restrict__ row_start,
                                                         int* __restrict__ cursor, int n) {
  __shared__ int sums[256];
  int tid = threadIdx.x;
  int base = blockIdx.x * 1024 + tid * 4;
  int v0 = 0, v1 = 0, v2 = 0, v3 = 0;
  if (base + 3 < n) {
    int4 t = *reinterpret_cast<const int4*>(cnt + base);
    v0 = t.x; v1 = t.y; v2 = t.z; v3 = t.w;
  } else {
    if (base + 0 < n) v0 = cnt[base + 0];
    if (base + 1 < n) v1 = cnt[base + 1];
    if (base + 2 < n) v2 = cnt[base + 2];
    if (base + 3 < n) v3 = cnt[base + 3];
  }
  int ls = v0 + v1 + v2 + v3;
  int orig = ls;
  sums[tid] = ls;
  __syncthreads();
  for (int off = 1; off < 256; off <<= 1) {
    int t = (tid >= off) ? sums[tid - off] : 0;
    __syncthreads();
    sums[tid] += t;
    __syncthreads();
  }
  int run = sums[tid] - orig + partials[blockIdx.x];
  if (base + 0 < n) { row_start[base + 0] = run; cursor[base + 0] = run; run += v0; }
  if (base + 1 < n) { row_start[base + 1] = run; cursor[base + 1] = run; run += v1; }
  if (base + 2 < n) { row_start[base + 2] = run; cursor[base + 2] = run; run += v2; }
  if (base + 3 < n) { row_start[base + 3] = run; cursor[base + 3] = run; run += v3; }
}

__global__ __launch_bounds__(256) void scatter_kernel(const int* __restrict__ erows,
                                                      const int* __restrict__ ecols,
                                                      const float* __restrict__ evals,
                                                      int* __restrict__ cursor,
                                                      int2* __restrict__ spack, int E) {
  int e = blockIdx.x * 256 + threadIdx.x;
  if (e >= E) return;
  int r = erows[e];
  int pos = atomicAdd(&cursor[r], 1);
  spack[pos] = make_int2(ecols[e], __float_as_int(evals[e]));
}

// ============ Gather SpMM (bf16 v, fp32 accum, +eps residual, bf16 agg out) ============
__global__ __launch_bounds__(256) void gather_kernel(const int* __restrict__ row_start,
                                                     const int2* __restrict__ spack,
                                                     const unsigned short* __restrict__ v_bf,
                                                     const float* __restrict__ eps_p,
                                                     unsigned short* __restrict__ agg_bf) {
  int wid = blockIdx.x * 4 + (threadIdx.x >> 6);
  if (wid >= N_NODES) return;
  int lane = threadIdx.x & 63;
  int s = row_start[wid];
  int e_end = row_start[wid + 1];
  const unsigned int* v32 = reinterpret_cast<const unsigned int*>(v_bf);
  float ax = 0.f, ay = 0.f;
  for (int e = s; e < e_end; ++e) {
    int2 p = spack[e];
    float w = __int_as_float(p.y);
    unsigned int t = v32[(size_t)p.x * 64 + lane];
    ax += w * bf2f((unsigned short)(t & 0xffff));
    ay += w * bf2f((unsigned short)(t >> 16));
  }
  float eps = eps_p[0];
  unsigned int tv = v32[(size_t)wid * 64 + lane];
  ax += eps * bf2f((unsigned short)(tv & 0xffff));
  ay += eps * bf2f((unsigned short)(tv >> 16));
  unsigned int o = (unsigned int)f2bf(ax) | ((unsigned int)f2bf(ay) << 16);
  reinterpret_cast<unsigned int*>(agg_bf)[(size_t)wid * 64 + lane] = o;
}

// ============ GEMM1: h1_bf = bf16(agg_bf @ W1 + b1)  [MFMA 16x16x32] ============
// block = 256 thr = 4 waves; wave -> 16 rows x 256 cols; K=128 (4 steps)
__global__ __launch_bounds__(256) void gemm1_kernel(const unsigned short* __restrict__ agg_bf,
                                                    const unsigned short* __restrict__ w1t,
                                                    const float* __restrict__ b1,
                                                    unsigned short* __restrict__ h1_bf) {
  __shared__ unsigned short lds[4 * 16 * 264];
  int tid = threadIdx.x;
  int wid = tid >> 6;
  int lane = tid & 63;
  int m15 = lane & 15;
  int g8 = (lane >> 4) * 8;
  int rowbase = blockIdx.x * 64 + wid * 16;

  f32x4 acc[16];
#pragma unroll
  for (int t = 0; t < 16; ++t) acc[t] = (f32x4){0.f, 0.f, 0.f, 0.f};

  const short8* Abase = reinterpret_cast<const short8*>(agg_bf + (size_t)(rowbase + m15) * 128 + g8);
#pragma unroll
  for (int s = 0; s < 4; ++s) {
    short8 a = Abase[s * 4];  // +s*32 elems = +4 short8
#pragma unroll
    for (int t = 0; t < 16; ++t) {
      short8 b = *reinterpret_cast<const short8*>(w1t + (size_t)(t * 16 + m15) * 128 + s * 32 + g8);
      acc[t] = __builtin_amdgcn_mfma_f32_16x16x32_bf16(a, b, acc[t], 0, 0, 0);
    }
  }

  // epilogue: +b1, cvt bf16, LDS repack, coalesced store
  unsigned short* myl = lds + wid * 16 * 264;
#pragma unroll
  for (int t = 0; t < 16; ++t) {
    int col = t * 16 + m15;
    float bias = b1[col];
#pragma unroll
    for (int r = 0; r < 4; ++r) {
      int rl = (lane >> 4) * 4 + r;
      myl[rl * 264 + col] = f2bf(acc[t][r] + bias);
    }
  }
  __syncthreads();
#pragma unroll
  for (int i = 0; i < 8; ++i) {
    int rl = i * 2 + (lane >> 5);
    int row = rowbase + rl;
    if (row < N_NODES) {
      *reinterpret_cast<short8*>(h1_bf + (size_t)row * 256 + (lane & 31) * 8) =
          *reinterpret_cast<const short8*>(myl + rl * 264 + (lane & 31) * 8);
    }
  }
}

// ============ GEMM2: out = relu(bn1(h1_bf)) @ W2 + b2  (raw fp32, pre-BN2) ============
// block = 256 thr = 4 waves; wave -> 16 rows x 128 cols; K=256 (8 steps)
__global__ __launch_bounds__(256) void gemm2_kernel(const unsigned short* __restrict__ h1_bf,
                                                    const float* __restrict__ ss1,
                                                    const unsigned short* __restrict__ w2t,
                                                    const float* __restrict__ b2,
                                                    float* __restrict__ out) {
  __shared__ float lds[4 * 16 * 132];
  int tid = threadIdx.x;
  int wid = tid >> 6;
  int lane = tid & 63;
  int m15 = lane & 15;
  int g8 = (lane >> 4) * 8;
  int rowbase = blockIdx.x * 64 + wid * 16;

  f32x4 acc[8];
#pragma unroll
  for (int t = 0; t < 8; ++t) acc[t] = (f32x4){0.f, 0.f, 0.f, 0.f};

  const unsigned short* Arow = h1_bf + (size_t)(rowbase + m15) * 256;
#pragma unroll
  for (int s = 0; s < 8; ++s) {
    int k0 = s * 32 + g8;
    short8 raw = *reinterpret_cast<const short8*>(Arow + k0);
    float4 sc0 = *reinterpret_cast<const float4*>(ss1 + k0);
    float4 sc1 = *reinterpret_cast<const float4*>(ss1 + k0 + 4);
    float4 sh0 = *reinterpret_cast<const float4*>(ss1 + 256 + k0);
    float4 sh1 = *reinterpret_cast<const float4*>(ss1 + 256 + k0 + 4);
    short8 a;
    a[0] = (short)f2bf(fmaxf(bf2f((unsigned short)raw[0]) * sc0.x + sh0.x, 0.f));
    a[1] = (short)f2bf(fmaxf(bf2f((unsigned short)raw[1]) * sc0.y + sh0.y, 0.f));
    a[2] = (short)f2bf(fmaxf(bf2f((unsigned short)raw[2]) * sc0.z + sh0.z, 0.f));
    a[3] = (short)f2bf(fmaxf(bf2f((unsigned short)raw[3]) * sc0.w + sh0.w, 0.f));
    a[4] = (short)f2bf(fmaxf(bf2f((unsigned short)raw[4]) * sc1.x + sh1.x, 0.f));
    a[5] = (short)f2bf(fmaxf(bf2f((unsigned short)raw[5]) * sc1.y + sh1.y, 0.f));
    a[6] = (short)f2bf(fmaxf(bf2f((unsigned short)raw[6]) * sc1.z + sh1.z, 0.f));
    a[7] = (short)f2bf(fmaxf(bf2f((unsigned short)raw[7]) * sc1.w + sh1.w, 0.f));
#pragma unroll
    for (int t = 0; t < 8; ++t) {
      short8 b = *reinterpret_cast<const short8*>(w2t + (size_t)(t * 16 + m15) * 256 + s * 32 + g8);
      acc[t] = __builtin_amdgcn_mfma_f32_16x16x32_bf16(a, b, acc[t], 0, 0, 0);
    }
  }

  float* myl = lds + wid * 16 * 132;
#pragma unroll
  for (int t = 0; t < 8; ++t) {
    int col = t * 16 + m15;
    float bias = b2[col];
#pragma unroll
    for (int r = 0; r < 4; ++r) {
      int rl = (lane >> 4) * 4 + r;
      myl[rl * 132 + col] = acc[t][r] + bias;
    }
  }
  __syncthreads();
#pragma unroll
  for (int i = 0; i < 8; ++i) {
    int rl = i * 2 + (lane >> 5);
    int row = rowbase + rl;
    if (row < N_NODES) {
      *reinterpret_cast<float4*>(out + (size_t)row * 128 + (lane & 31) * 4) =
          *reinterpret_cast<const float4*>(myl + rl * 132 + (lane & 31) * 4);
    }
  }
}

// ============ column stats ============
__global__ void colstats_bf_kernel(const unsigned short* __restrict__ x, int rows,
                                   float* __restrict__ stats) {
  int col = threadIdx.x;  // blockDim == 256
  float s = 0.f, s2 = 0.f;
  for (int r = blockIdx.x; r < rows; r += gridDim.x) {
    float val = bf2f(x[(size_t)r * 256 + col]);
    s += val;
    s2 += val * val;
  }
  atomicAdd(&stats[col], s);
  atomicAdd(&stats[256 + col], s2);
}

__global__ void colstats_f32_kernel(const float* __restrict__ x, int rows,
                                    float* __restrict__ stats) {
  int col = threadIdx.x;  // blockDim == 128
  float s = 0.f, s2 = 0.f;
  for (int r = blockIdx.x; r < rows; r += gridDim.x) {
    float val = x[(size_t)r * 128 + col];
    s += val;
    s2 += val * val;
  }
  atomicAdd(&stats[col], s);
  atomicAdd(&stats[128 + col], s2);
}

template <int C>
__global__ void finalize_kernel(const float* __restrict__ stats,
                                const float* __restrict__ g,
                                const float* __restrict__ be,
                                float* __restrict__ ss) {
  int j = threadIdx.x;
  float inv_n = 1.0f / (float)N_NODES;
  float mu = stats[j] * inv_n;
  float var = stats[C + j] * inv_n - mu * mu;
  float sc = g[j] * rsqrtf(var + BN_EPS);
  ss[j] = sc;
  ss[C + j] = be[j] - mu * sc;
}

__global__ __launch_bounds__(256) void bnrelu_kernel(float* __restrict__ out,
                                                     const float* __restrict__ ss) {
  __shared__ float sc[D_OUTC], sh[D_OUTC];
  if (threadIdx.x < D_OUTC) {
    sc[threadIdx.x] = ss[threadIdx.x];
    sh[threadIdx.x] = ss[D_OUTC + threadIdx.x];
  }
  __syncthreads();
  size_t total = (size_t)N_NODES * (D_OUTC / 4);
  for (size_t i = (size_t)blockIdx.x * blockDim.x + threadIdx.x; i < total;
       i += (size_t)gridDim.x * blockDim.x) {
    float4 o = reinterpret_cast<float4*>(out)[i];
    int c = ((int)(i & 31)) * 4;
    o.x = fmaxf(o.x * sc[c + 0] + sh[c + 0], 0.f);
    o.y = fmaxf(o.y * sc[c + 1] + sh[c + 1], 0.f);
    o.z = fmaxf(o.z * sc[c + 2] + sh[c + 2], 0.f);
    o.w = fmaxf(o.w * sc[c + 3] + sh[c + 3], 0.f);
    reinterpret_cast<float4*>(out)[i] = o;
  }
}

extern "C" void kernel_launch(void* const* d_in, const int* in_sizes, int n_in,
                              void* d_out, int out_size, void* d_ws, size_t ws_size,
                              hipStream_t stream) {
  const float* v = (const float*)d_in[0];
  const int* erows = (const int*)d_in[1];
  const int* ecols = (const int*)d_in[2];
  const float* evals = (const float*)d_in[3];
  const float* eps = (const float*)d_in[4];
  const float* W1 = (const float*)d_in[5];
  const float* b1 = (const float*)d_in[6];
  const float* g1 = (const float*)d_in[7];
  const float* be1 = (const float*)d_in[8];
  const float* W2 = (const float*)d_in[9];
  const float* b2 = (const float*)d_in[10];
  const float* g2 = (const float*)d_in[11];
  const float* be2 = (const float*)d_in[12];
  float* out = (float*)d_out;
  int E = in_sizes[1];

  char* ws = (char*)d_ws;
  unsigned short* agg_bf = (unsigned short*)(ws + 0);            // 25.6 MB
  unsigned short* v_bf = (unsigned short*)(ws + 25600000);       // 25.6 MB
  unsigned short* h1_bf = (unsigned short*)(ws + 51200000);      // 51.2 MB
  int2* spack = (int2*)h1_bf;                                    // overlay (12.8 MB)
  unsigned short* w1t = (unsigned short*)(ws + 102400000);       // 64 KB
  unsigned short* w2t = (unsigned short*)(ws + 102465536);       // 64 KB
  float* stats1 = (float*)(ws + 102531072);                      // 512 f
  float* ss1 = (float*)(ws + 102533120);                         // 512 f
  float* stats2 = (float*)(ws + 102535168);                      // 256 f
  float* ss2 = (float*)(ws + 102536192);                         // 256 f
  int* row_start = (int*)(ws + 102537216);                       // 100004 ints
  int* cursor = (int*)(ws + 102937232);                          // 100000 ints
  int* partials = (int*)(ws + 103337232);                        // 128 ints

  const int NB = (N_NODES + 1023) / 1024;  // 98

  hipMemsetAsync(stats1, 0, 6144, stream);
  hipMemsetAsync(cursor, 0, N_NODES * sizeof(int), stream);

  // conversions
  conv_v_kernel<<<(N_NODES * D_IN / 8 + 255) / 256, 256, 0, stream>>>(v, v_bf);
  conv_w_kernel<<<(2 * 128 * 256) / 256, 256, 0, stream>>>(W1, W2, w1t, w2t);

  // CSR build
  hist_kernel<<<(E + 255) / 256, 256, 0, stream>>>(erows, cursor, E);
  scan_reduce_kernel<<<NB, 256, 0, stream>>>(cursor, partials, N_NODES);
  scan_partials_kernel<<<1, 128, 0, stream>>>(partials, NB, row_start, N_NODES, E);
  scan_block_kernel<<<NB, 256, 0, stream>>>(cursor, partials, row_start, cursor, N_NODES);
  scatter_kernel<<<(E + 255) / 256, 256, 0, stream>>>(erows, ecols, evals, cursor, spack, E);

  // gather SpMM (atomic-free, bf16)
  gather_kernel<<<(N_NODES + 3) / 4, 256, 0, stream>>>(row_start, spack, v_bf, eps, agg_bf);

  // GEMM1 (MFMA) -> h1_bf
  gemm1_kernel<<<(N_NODES + 63) / 64, 256, 0, stream>>>(agg_bf, w1t, b1, h1_bf);
  // BN1 stats
  colstats_bf_kernel<<<1024, 256, 0, stream>>>(h1_bf, N_NODES, stats1);
  finalize_kernel<D_HID><<<1, D_HID, 0, stream>>>(stats1, g1, be1, ss1);
  // GEMM2 (MFMA, fused BN1+ReLU on A) -> raw out
  gemm2_kernel<<<(N_NODES + 63) / 64, 256, 0, stream>>>(h1_bf, ss1, w2t, b2, out);
  // BN2 stats + finalize + in-place BN2+ReLU
  colstats_f32_kernel<<<1024, 128, 0, stream>>>(out, N_NODES, stats2);
  finalize_kernel<D_OUTC><<<1, D_OUTC, 0, stream>>>(stats2, g2, be2, ss2);
  bnrelu_kernel<<<2048, 256, 0, stream>>>(out, ss2);
}

// Round 4
// 462.345 us; speedup vs baseline: 6.4880x; 1.3572x over previous
//
#include <hip/hip_runtime.h>
#include <hip/hip_bf16.h>

#define N_NODES 100000
#define D_IN 128
#define D_HID 256
#define D_OUTC 128
#define BN_EPS 1e-5f

typedef __attribute__((ext_vector_type(8))) short short8;
typedef __attribute__((ext_vector_type(4))) float f32x4;

__device__ __forceinline__ unsigned short f2bf(float f) {
  unsigned int u = __float_as_uint(f);
  unsigned int r = u + 0x7fffu + ((u >> 16) & 1u);
  return (unsigned short)(r >> 16);
}
__device__ __forceinline__ float bf2f(unsigned int h) {
  return __uint_as_float(h << 16);
}

// ============ conversions ============
__global__ __launch_bounds__(256) void conv_v_kernel(const float* __restrict__ v,
                                                     unsigned short* __restrict__ v_bf) {
  int i = blockIdx.x * 256 + threadIdx.x;
  const float4* v4 = reinterpret_cast<const float4*>(v);
  float4 a = v4[i * 2];
  float4 b = v4[i * 2 + 1];
  short8 o;
  o[0] = (short)f2bf(a.x); o[1] = (short)f2bf(a.y);
  o[2] = (short)f2bf(a.z); o[3] = (short)f2bf(a.w);
  o[4] = (short)f2bf(b.x); o[5] = (short)f2bf(b.y);
  o[6] = (short)f2bf(b.z); o[7] = (short)f2bf(b.w);
  *reinterpret_cast<short8*>(v_bf + (size_t)i * 8) = o;
}

// transpose+convert W1[128,256]->w1t[256,128], W2[256,128]->w2t[128,256]
__global__ __launch_bounds__(256) void conv_w_kernel(const float* __restrict__ W1,
                                                     const float* __restrict__ W2,
                                                     unsigned short* __restrict__ w1t,
                                                     unsigned short* __restrict__ w2t) {
  int idx = blockIdx.x * 256 + threadIdx.x;
  if (idx < 128 * 256) {
    int n = idx >> 7, k = idx & 127;
    w1t[idx] = f2bf(W1[(size_t)k * 256 + n]);
  } else {
    int i2 = idx - 128 * 256;
    int n = i2 >> 8, k = i2 & 255;
    w2t[i2] = f2bf(W2[(size_t)k * 128 + n]);
  }
}

// ============ CSR build ============
__global__ __launch_bounds__(256) void hist_kernel(const int* __restrict__ erows,
                                                   int* __restrict__ cnt, int E) {
  int e = blockIdx.x * 256 + threadIdx.x;
  if (e < E) atomicAdd(&cnt[erows[e]], 1);
}

__global__ __launch_bounds__(256) void scan_reduce_kernel(const int* __restrict__ cnt,
                                                          int* __restrict__ partials, int n) {
  __shared__ int red[256];
  int tid = threadIdx.x;
  int base = blockIdx.x * 1024 + tid * 4;
  int s = 0;
  if (base + 3 < n) {
    int4 t = *reinterpret_cast<const int4*>(cnt + base);
    s = t.x + t.y + t.z + t.w;
  } else {
    for (int i = 0; i < 4; ++i)
      if (base + i < n) s += cnt[base + i];
  }
  red[tid] = s;
  __syncthreads();
  for (int off = 128; off > 0; off >>= 1) {
    if (tid < off) red[tid] += red[tid + off];
    __syncthreads();
  }
  if (tid == 0) partials[blockIdx.x] = red[0];
}

__global__ __launch_bounds__(128) void scan_partials_kernel(int* __restrict__ partials, int nb,
                                                            int* __restrict__ row_start, int n,
                                                            int E) {
  __shared__ int buf[128];
  int tid = threadIdx.x;
  int orig = (tid < nb) ? partials[tid] : 0;
  buf[tid] = orig;
  __syncthreads();
  for (int off = 1; off < 128; off <<= 1) {
    int t = (tid >= off) ? buf[tid - off] : 0;
    __syncthreads();
    buf[tid] += t;
    __syncthreads();
  }
  if (tid < nb) partials[tid] = buf[tid] - orig;
  if (tid == 0) row_start[n] = E;
}

__global__ __launch_bounds__(256) void scan_block_kernel(const int* __restrict__ cnt,
                                                         const int* __restrict__ partials,
                                                         int* __restrict__ row_start,
                                                         int* __restrict__ cursor, int n) {
  __shared__ int sums[256];
  int tid = threadIdx.x;
  int base = blockIdx.x * 1024 + tid * 4;
  int v0 = 0, v1 = 0, v2 = 0, v3 = 0;
  if (base + 3 < n) {
    int4 t = *reinterpret_cast<const int4*>(cnt + base);
    v0 = t.x; v1 = t.y; v2 = t.z; v3 = t.w;
  } else {
    if (base + 0 < n) v0 = cnt[base + 0];
    if (base + 1 < n) v1 = cnt[base + 1];
    if (base + 2 < n) v2 = cnt[base + 2];
    if (base + 3 < n) v3 = cnt[base + 3];
  }
  int ls = v0 + v1 + v2 + v3;
  int orig = ls;
  sums[tid] = ls;
  __syncthreads();
  for (int off = 1; off < 256; off <<= 1) {
    int t = (tid >= off) ? sums[tid - off] : 0;
    __syncthreads();
    sums[tid] += t;
    __syncthreads();
  }
  int run = sums[tid] - orig + partials[blockIdx.x];
  if (base + 0 < n) { row_start[base + 0] = run; cursor[base + 0] = run; run += v0; }
  if (base + 1 < n) { row_start[base + 1] = run; cursor[base + 1] = run; run += v1; }
  if (base + 2 < n) { row_start[base + 2] = run; cursor[base + 2] = run; run += v2; }
  if (base + 3 < n) { row_start[base + 3] = run; cursor[base + 3] = run; run += v3; }
}

__global__ __launch_bounds__(256) void scatter_kernel(const int* __restrict__ erows,
                                                      const int* __restrict__ ecols,
                                                      const float* __restrict__ evals,
                                                      int* __restrict__ cursor,
                                                      int2* __restrict__ spack, int E) {
  int e = blockIdx.x * 256 + threadIdx.x;
  if (e >= E) return;
  int r = erows[e];
  int pos = atomicAdd(&cursor[r], 1);
  spack[pos] = make_int2(ecols[e], __float_as_int(evals[e]));
}

// ============ Gather SpMM: wave handles 1 row, 2 edges/iter x2 unroll ============
__global__ __launch_bounds__(256) void gather_kernel(const int* __restrict__ row_start,
                                                     const int2* __restrict__ spack,
                                                     const unsigned short* __restrict__ v_bf,
                                                     const float* __restrict__ eps_p,
                                                     unsigned short* __restrict__ agg_bf,
                                                     int E) {
  int wid = blockIdx.x * 4 + (threadIdx.x >> 6);
  if (wid >= N_NODES) return;
  int lane = threadIdx.x & 63;
  int half = lane >> 5;   // which edge of the pair
  int l5 = lane & 31;     // 8B feature chunk (4 feats)
  int s = row_start[wid];
  int e_end = row_start[wid + 1];
  const uint2* v64 = reinterpret_cast<const uint2*>(v_bf);  // row = 32 uint2

  float a0 = 0.f, a1 = 0.f, a2 = 0.f, a3 = 0.f;
  for (int e = s; e < e_end; e += 4) {
    int i0 = e + half;
    int i1 = e + 2 + half;
    int c0 = min(i0, E - 1);
    int c1 = min(i1, E - 1);
    int2 p0 = spack[c0];
    int2 p1 = spack[c1];
    float w0 = (i0 < e_end) ? __int_as_float(p0.y) : 0.f;
    float w1 = (i1 < e_end) ? __int_as_float(p1.y) : 0.f;
    uint2 t0 = v64[(size_t)p0.x * 32 + l5];
    uint2 t1 = v64[(size_t)p1.x * 32 + l5];
    a0 += w0 * bf2f(t0.x & 0xffffu);
    a1 += w0 * bf2f(t0.x >> 16);
    a2 += w0 * bf2f(t0.y & 0xffffu);
    a3 += w0 * bf2f(t0.y >> 16);
    a0 += w1 * bf2f(t1.x & 0xffffu);
    a1 += w1 * bf2f(t1.x >> 16);
    a2 += w1 * bf2f(t1.y & 0xffffu);
    a3 += w1 * bf2f(t1.y >> 16);
  }
  // cross-half reduce
  a0 += __shfl_xor(a0, 32);
  a1 += __shfl_xor(a1, 32);
  a2 += __shfl_xor(a2, 32);
  a3 += __shfl_xor(a3, 32);
  if (half == 0) {
    float eps = eps_p[0];
    uint2 tv = v64[(size_t)wid * 32 + l5];
    a0 += eps * bf2f(tv.x & 0xffffu);
    a1 += eps * bf2f(tv.x >> 16);
    a2 += eps * bf2f(tv.y & 0xffffu);
    a3 += eps * bf2f(tv.y >> 16);
    uint2 o;
    o.x = (unsigned int)f2bf(a0) | ((unsigned int)f2bf(a1) << 16);
    o.y = (unsigned int)f2bf(a2) | ((unsigned int)f2bf(a3) << 16);
    reinterpret_cast<uint2*>(agg_bf)[(size_t)wid * 32 + l5] = o;
  }
}

// ============ GEMM1: h1_bf = bf16(agg_bf @ W1 + b1)  [MFMA, B in swizzled LDS] ============
__global__ __launch_bounds__(256) void gemm1_kernel(const unsigned short* __restrict__ agg_bf,
                                                    const unsigned short* __restrict__ w1t,
                                                    const float* __restrict__ b1,
                                                    unsigned short* __restrict__ h1_bf) {
  __shared__ unsigned char smem[65536];
  int tid = threadIdx.x;
  int wid = tid >> 6;
  int lane = tid & 63;
  int m15 = lane & 15;
  int g8 = (lane >> 4) * 8;       // elem offset of 8-elem chunk
  int g16 = (lane >> 4) * 16;     // byte offset
  int rowbase = blockIdx.x * 64 + wid * 16;

  // stage w1t (256 rows x 256B) into LDS, XOR-swizzled
  {
    const float4* src = reinterpret_cast<const float4*>(w1t);  // 4096 x 16B
#pragma unroll
    for (int it = 0; it < 16; ++it) {
      int i = it * 256 + tid;
      int row = i >> 4;
      int cb = (i & 15) << 4;
      float4 d = src[i];
      *reinterpret_cast<float4*>(smem + row * 256 + (cb ^ ((row & 7) << 4))) = d;
    }
  }
  __syncthreads();

  f32x4 acc[16];
#pragma unroll
  for (int t = 0; t < 16; ++t) acc[t] = (f32x4){0.f, 0.f, 0.f, 0.f};

  const short8* Abase = reinterpret_cast<const short8*>(agg_bf + (size_t)(rowbase + m15) * 128 + g8);
#pragma unroll
  for (int s = 0; s < 4; ++s) {
    short8 a = Abase[s * 4];
#pragma unroll
    for (int t = 0; t < 16; ++t) {
      int brow = t * 16 + m15;
      short8 b = *reinterpret_cast<const short8*>(
          smem + brow * 256 + ((s * 64 + g16) ^ ((brow & 7) << 4)));
      acc[t] = __builtin_amdgcn_mfma_f32_16x16x32_bf16(a, b, acc[t], 0, 0, 0);
    }
  }
  __syncthreads();  // B-LDS dead, reuse for epilogue repack

  unsigned short* myl = reinterpret_cast<unsigned short*>(smem) + wid * 16 * 264;
#pragma unroll
  for (int t = 0; t < 16; ++t) {
    int col = t * 16 + m15;
    float bias = b1[col];
#pragma unroll
    for (int r = 0; r < 4; ++r) {
      int rl = (lane >> 4) * 4 + r;
      myl[rl * 264 + col] = f2bf(acc[t][r] + bias);
    }
  }
  __syncthreads();
#pragma unroll
  for (int i = 0; i < 8; ++i) {
    int rl = i * 2 + (lane >> 5);
    int row = rowbase + rl;
    if (row < N_NODES) {
      *reinterpret_cast<short8*>(h1_bf + (size_t)row * 256 + (lane & 31) * 8) =
          *reinterpret_cast<const short8*>(myl + rl * 264 + (lane & 31) * 8);
    }
  }
}

// ============ GEMM2: out = relu(bn1(h1_bf)) @ W2 + b2 (raw fp32) [B in swizzled LDS] ============
__global__ __launch_bounds__(256) void gemm2_kernel(const unsigned short* __restrict__ h1_bf,
                                                    const float* __restrict__ ss1,
                                                    const unsigned short* __restrict__ w2t,
                                                    const float* __restrict__ b2,
                                                    float* __restrict__ out) {
  __shared__ unsigned char smem[65536];
  int tid = threadIdx.x;
  int wid = tid >> 6;
  int lane = tid & 63;
  int m15 = lane & 15;
  int g8 = (lane >> 4) * 8;
  int g16 = (lane >> 4) * 16;
  int rowbase = blockIdx.x * 64 + wid * 16;

  // stage w2t (128 rows x 512B) into LDS, XOR-swizzled
  {
    const float4* src = reinterpret_cast<const float4*>(w2t);  // 4096 x 16B
#pragma unroll
    for (int it = 0; it < 16; ++it) {
      int i = it * 256 + tid;
      int row = i >> 5;
      int cb = (i & 31) << 4;
      float4 d = src[i];
      *reinterpret_cast<float4*>(smem + row * 512 + (cb ^ ((row & 7) << 4))) = d;
    }
  }
  __syncthreads();

  f32x4 acc[8];
#pragma unroll
  for (int t = 0; t < 8; ++t) acc[t] = (f32x4){0.f, 0.f, 0.f, 0.f};

  const unsigned short* Arow = h1_bf + (size_t)(rowbase + m15) * 256;
#pragma unroll
  for (int s = 0; s < 8; ++s) {
    int k0 = s * 32 + g8;
    short8 raw = *reinterpret_cast<const short8*>(Arow + k0);
    float4 sc0 = *reinterpret_cast<const float4*>(ss1 + k0);
    float4 sc1 = *reinterpret_cast<const float4*>(ss1 + k0 + 4);
    float4 sh0 = *reinterpret_cast<const float4*>(ss1 + 256 + k0);
    float4 sh1 = *reinterpret_cast<const float4*>(ss1 + 256 + k0 + 4);
    short8 a;
    a[0] = (short)f2bf(fmaxf(bf2f((unsigned short)raw[0] & 0xffffu) * sc0.x + sh0.x, 0.f));
    a[1] = (short)f2bf(fmaxf(bf2f((unsigned short)raw[1] & 0xffffu) * sc0.y + sh0.y, 0.f));
    a[2] = (short)f2bf(fmaxf(bf2f((unsigned short)raw[2] & 0xffffu) * sc0.z + sh0.z, 0.f));
    a[3] = (short)f2bf(fmaxf(bf2f((unsigned short)raw[3] & 0xffffu) * sc0.w + sh0.w, 0.f));
    a[4] = (short)f2bf(fmaxf(bf2f((unsigned short)raw[4] & 0xffffu) * sc1.x + sh1.x, 0.f));
    a[5] = (short)f2bf(fmaxf(bf2f((unsigned short)raw[5] & 0xffffu) * sc1.y + sh1.y, 0.f));
    a[6] = (short)f2bf(fmaxf(bf2f((unsigned short)raw[6] & 0xffffu) * sc1.z + sh1.z, 0.f));
    a[7] = (short)f2bf(fmaxf(bf2f((unsigned short)raw[7] & 0xffffu) * sc1.w + sh1.w, 0.f));
#pragma unroll
    for (int t = 0; t < 8; ++t) {
      int brow = t * 16 + m15;
      short8 b = *reinterpret_cast<const short8*>(
          smem + brow * 512 + ((s * 64 + g16) ^ ((brow & 7) << 4)));
      acc[t] = __builtin_amdgcn_mfma_f32_16x16x32_bf16(a, b, acc[t], 0, 0, 0);
    }
  }
  __syncthreads();

  float* myl = reinterpret_cast<float*>(smem) + wid * 16 * 132;
#pragma unroll
  for (int t = 0; t < 8; ++t) {
    int col = t * 16 + m15;
    float bias = b2[col];
#pragma unroll
    for (int r = 0; r < 4; ++r) {
      int rl = (lane >> 4) * 4 + r;
      myl[rl * 132 + col] = acc[t][r] + bias;
    }
  }
  __syncthreads();
#pragma unroll
  for (int i = 0; i < 8; ++i) {
    int rl = i * 2 + (lane >> 5);
    int row = rowbase + rl;
    if (row < N_NODES) {
      *reinterpret_cast<float4*>(out + (size_t)row * 128 + (lane & 31) * 4) =
          *reinterpret_cast<const float4*>(myl + rl * 132 + (lane & 31) * 4);
    }
  }
}

// ============ column stats ============
__global__ void colstats_bf_kernel(const unsigned short* __restrict__ x, int rows,
                                   float* __restrict__ stats) {
  int col = threadIdx.x;  // blockDim == 256
  float s = 0.f, s2 = 0.f;
  for (int r = blockIdx.x; r < rows; r += gridDim.x) {
    float val = bf2f(x[(size_t)r * 256 + col]);
    s += val;
    s2 += val * val;
  }
  atomicAdd(&stats[col], s);
  atomicAdd(&stats[256 + col], s2);
}

__global__ void colstats_f32_kernel(const float* __restrict__ x, int rows,
                                    float* __restrict__ stats) {
  int col = threadIdx.x;  // blockDim == 128
  float s = 0.f, s2 = 0.f;
  for (int r = blockIdx.x; r < rows; r += gridDim.x) {
    float val = x[(size_t)r * 128 + col];
    s += val;
    s2 += val * val;
  }
  atomicAdd(&stats[col], s);
  atomicAdd(&stats[128 + col], s2);
}

template <int C>
__global__ void finalize_kernel(const float* __restrict__ stats,
                                const float* __restrict__ g,
                                const float* __restrict__ be,
                                float* __restrict__ ss) {
  int j = threadIdx.x;
  float inv_n = 1.0f / (float)N_NODES;
  float mu = stats[j] * inv_n;
  float var = stats[C + j] * inv_n - mu * mu;
  float sc = g[j] * rsqrtf(var + BN_EPS);
  ss[j] = sc;
  ss[C + j] = be[j] - mu * sc;
}

__global__ __launch_bounds__(256) void bnrelu_kernel(float* __restrict__ out,
                                                     const float* __restrict__ ss) {
  __shared__ float sc[D_OUTC], sh[D_OUTC];
  if (threadIdx.x < D_OUTC) {
    sc[threadIdx.x] = ss[threadIdx.x];
    sh[threadIdx.x] = ss[D_OUTC + threadIdx.x];
  }
  __syncthreads();
  size_t total = (size_t)N_NODES * (D_OUTC / 4);
  for (size_t i = (size_t)blockIdx.x * blockDim.x + threadIdx.x; i < total;
       i += (size_t)gridDim.x * blockDim.x) {
    float4 o = reinterpret_cast<float4*>(out)[i];
    int c = ((int)(i & 31)) * 4;
    o.x = fmaxf(o.x * sc[c + 0] + sh[c + 0], 0.f);
    o.y = fmaxf(o.y * sc[c + 1] + sh[c + 1], 0.f);
    o.z = fmaxf(o.z * sc[c + 2] + sh[c + 2], 0.f);
    o.w = fmaxf(o.w * sc[c + 3] + sh[c + 3], 0.f);
    reinterpret_cast<float4*>(out)[i] = o;
  }
}

extern "C" void kernel_launch(void* const* d_in, const int* in_sizes, int n_in,
                              void* d_out, int out_size, void* d_ws, size_t ws_size,
                              hipStream_t stream) {
  const float* v = (const float*)d_in[0];
  const int* erows = (const int*)d_in[1];
  const int* ecols = (const int*)d_in[2];
  const float* evals = (const float*)d_in[3];
  const float* eps = (const float*)d_in[4];
  const float* W1 = (const float*)d_in[5];
  const float* b1 = (const float*)d_in[6];
  const float* g1 = (const float*)d_in[7];
  const float* be1 = (const float*)d_in[8];
  const float* W2 = (const float*)d_in[9];
  const float* b2 = (const float*)d_in[10];
  const float* g2 = (const float*)d_in[11];
  const float* be2 = (const float*)d_in[12];
  float* out = (float*)d_out;
  int E = in_sizes[1];

  char* ws = (char*)d_ws;
  unsigned short* agg_bf = (unsigned short*)(ws + 0);            // 25.6 MB
  unsigned short* v_bf = (unsigned short*)(ws + 25600000);       // 25.6 MB
  unsigned short* h1_bf = (unsigned short*)(ws + 51200000);      // 51.2 MB
  int2* spack = (int2*)h1_bf;                                    // overlay (12.8 MB)
  unsigned short* w1t = (unsigned short*)(ws + 102400000);       // 64 KB
  unsigned short* w2t = (unsigned short*)(ws + 102465536);       // 64 KB
  float* stats1 = (float*)(ws + 102531072);
  float* ss1 = (float*)(ws + 102533120);
  float* stats2 = (float*)(ws + 102535168);
  float* ss2 = (float*)(ws + 102536192);
  int* row_start = (int*)(ws + 102537216);                       // 100001 ints
  int* cursor = (int*)(ws + 102937232);                          // 100000 ints
  int* partials = (int*)(ws + 103337232);                        // 128 ints

  const int NB = (N_NODES + 1023) / 1024;  // 98

  hipMemsetAsync(stats1, 0, 6144, stream);
  hipMemsetAsync(cursor, 0, N_NODES * sizeof(int), stream);

  conv_v_kernel<<<(N_NODES * D_IN / 8 + 255) / 256, 256, 0, stream>>>(v, v_bf);
  conv_w_kernel<<<(2 * 128 * 256) / 256, 256, 0, stream>>>(W1, W2, w1t, w2t);

  hist_kernel<<<(E + 255) / 256, 256, 0, stream>>>(erows, cursor, E);
  scan_reduce_kernel<<<NB, 256, 0, stream>>>(cursor, partials, N_NODES);
  scan_partials_kernel<<<1, 128, 0, stream>>>(partials, NB, row_start, N_NODES, E);
  scan_block_kernel<<<NB, 256, 0, stream>>>(cursor, partials, row_start, cursor, N_NODES);
  scatter_kernel<<<(E + 255) / 256, 256, 0, stream>>>(erows, ecols, evals, cursor, spack, E);

  gather_kernel<<<(N_NODES + 3) / 4, 256, 0, stream>>>(row_start, spack, v_bf, eps, agg_bf, E);

  gemm1_kernel<<<(N_NODES + 63) / 64, 256, 0, stream>>>(agg_bf, w1t, b1, h1_bf);
  colstats_bf_kernel<<<1024, 256, 0, stream>>>(h1_bf, N_NODES, stats1);
  finalize_kernel<D_HID><<<1, D_HID, 0, stream>>>(stats1, g1, be1, ss1);
  gemm2_kernel<<<(N_NODES + 63) / 64, 256, 0, stream>>>(h1_bf, ss1, w2t, b2, out);
  colstats_f32_kernel<<<1024, 128, 0, stream>>>(out, N_NODES, stats2);
  finalize_kernel<D_OUTC><<<1, D_OUTC, 0, stream>>>(stats2, g2, be2, ss2);
  bnrelu_kernel<<<2048, 256, 0, stream>>>(out, ss2);
}